// Round 1
// baseline (303.822 us; speedup 1.0000x reference)
//
#include <hip/hip_runtime.h>
#include <cstdint>
#include <cstddef>

// Problem constants (B=8192, P=8192, F=256; SIGMA=1 -> denom = 2)
#define B_ROWS 8192
#define P_ROWS 8192
#define FDIM   256

// GEMM tiling (m97-ladder structure: 128x128 tile, 4 waves, 4x4 16x16x32 MFMA)
#define BM 128
#define BN 128
#define BK 64
#define NSTEP (FDIM / BK)   // 4 K-steps

typedef __bf16  bf16x8  __attribute__((ext_vector_type(8)));
typedef float   floatx4 __attribute__((ext_vector_type(4)));

// round-to-nearest-even fp32 -> bf16 (inputs are finite Gaussians, no NaN path)
__device__ __forceinline__ unsigned short f2bf(float f) {
  unsigned int u = __float_as_uint(f);
  u += 0x7fffu + ((u >> 16) & 1u);
  return (unsigned short)(u >> 16);
}

// async global->LDS, 16B per lane. LDS dest is wave-uniform base + lane*16.
__device__ __forceinline__ void async16(const void* g, void* l) {
  __builtin_amdgcn_global_load_lds(
      (const __attribute__((address_space(1))) void*)g,
      (__attribute__((address_space(3))) void*)l,
      16, 0, 0);
}

// ---------------------------------------------------------------------------
// Pre-pass: convert x / prototypes to bf16 planes in ws, compute fp32 row
// norms. One wave per row (64 lanes x float4 = 256 elems).
// ---------------------------------------------------------------------------
__global__ void __launch_bounds__(64) prep_kernel(
    const float* __restrict__ x, const float* __restrict__ p,
    unsigned short* __restrict__ xbf, unsigned short* __restrict__ pbf,
    float* __restrict__ x2, float* __restrict__ p2) {
  const int row  = blockIdx.x;
  const int lane = threadIdx.x;

  const float* src;
  unsigned short* dst;
  float* nrm;
  int r;
  if (row < B_ROWS) { src = x; dst = xbf; nrm = x2; r = row; }
  else              { src = p; dst = pbf; nrm = p2; r = row - B_ROWS; }

  const float4 v = *reinterpret_cast<const float4*>(src + (size_t)r * FDIM + lane * 4);
  float s = v.x * v.x + v.y * v.y + v.z * v.z + v.w * v.w;
  #pragma unroll
  for (int o = 32; o > 0; o >>= 1) s += __shfl_down(s, o);
  if (lane == 0) nrm[r] = s;

  ushort4 pk;
  pk.x = f2bf(v.x); pk.y = f2bf(v.y); pk.z = f2bf(v.z); pk.w = f2bf(v.w);
  *reinterpret_cast<ushort4*>(dst + (size_t)r * FDIM + lane * 4) = pk;
}

// ---------------------------------------------------------------------------
// Main kernel: C = X * P^T (both K-contiguous) with distance+exp epilogue.
//
// LDS layout: [row][8 chunks of 16B] per BK=64 K-slice. Chunk slot c of row r
// holds GLOBAL chunk (c ^ (r&7))  -> XOR swizzle. This keeps the
// global_load_lds constraint (LDS dest strictly lane-ordered; the *global*
// address per lane is free) while making the ds_read_b128 fragment reads
// 2-way bank-aliased (free, m136) instead of 16-way with a 128B row stride.
// ---------------------------------------------------------------------------
__global__ void __launch_bounds__(256) gauss_kernel(
    const unsigned short* __restrict__ xbf, const unsigned short* __restrict__ pbf,
    const float* __restrict__ x2, const float* __restrict__ p2,
    float* __restrict__ out) {
  __shared__ __align__(16) unsigned short lds_a[BM * BK];  // 16 KiB
  __shared__ __align__(16) unsigned short lds_b[BN * BK];  // 16 KiB

  const int t    = threadIdx.x;
  const int lane = t & 63;
  const int w    = t >> 6;        // wave 0..3
  const int wr   = w >> 1;        // wave row (0..1) -> 64-row slab of M
  const int wc   = w & 1;         // wave col (0..1) -> 64-col slab of N
  const int lm   = lane & 15;     // MFMA row/col-in-16
  const int q    = lane >> 4;     // quad 0..3
  const int sx   = lane & 7;      // swizzle xor (== row&7 for this lane's rows)

  const int M0 = blockIdx.y * BM;
  const int N0 = blockIdx.x * BN;

  // Staging addresses: 1024 16B chunks per operand per K-step.
  // Chunk id L = issue*256 + w*64 + lane; LDS placement is exactly lane order.
  const unsigned short* aSrc[4];
  const unsigned short* bSrc[4];
  int ldsOff[4];
  #pragma unroll
  for (int I = 0; I < 4; ++I) {
    const int L = I * 256 + w * 64 + lane;
    const int r = L >> 3;
    const int c = L & 7;
    const int g = c ^ (r & 7);            // global chunk to fetch for slot c
    aSrc[I] = xbf + (size_t)(M0 + r) * FDIM + g * 8;
    bSrc[I] = pbf + (size_t)(N0 + r) * FDIM + g * 8;
    ldsOff[I] = (I * 256 + w * 64) * 8;   // wave-uniform base (ushort elems)
  }

  floatx4 acc[4][4] = {};

  for (int s = 0; s < NSTEP; ++s) {
    __syncthreads();  // previous iteration's ds_reads complete before overwrite
    #pragma unroll
    for (int I = 0; I < 4; ++I) async16(aSrc[I] + s * BK, &lds_a[ldsOff[I]]);
    #pragma unroll
    for (int I = 0; I < 4; ++I) async16(bSrc[I] + s * BK, &lds_b[ldsOff[I]]);
    __syncthreads();  // drains vmcnt -> staged data visible

    #pragma unroll
    for (int kk = 0; kk < 2; ++kk) {   // two K=32 MFMA windows per BK=64
      const int slot = ((kk * 4 + q) ^ sx) * 8;      // swizzled 16B chunk
      const int aoff = (wr * 64 + lm) * BK + slot;
      const int boff = (wc * 64 + lm) * BK + slot;
      bf16x8 af[4], bfr[4];
      #pragma unroll
      for (int i = 0; i < 4; ++i) af[i]  = *(const bf16x8*)&lds_a[aoff + i * 16 * BK];
      #pragma unroll
      for (int j = 0; j < 4; ++j) bfr[j] = *(const bf16x8*)&lds_b[boff + j * 16 * BK];
      #pragma unroll
      for (int i = 0; i < 4; ++i)
        #pragma unroll
        for (int j = 0; j < 4; ++j)
          acc[i][j] = __builtin_amdgcn_mfma_f32_16x16x32_bf16(af[i], bfr[j], acc[i][j], 0, 0, 0);
    }
  }

  // Epilogue. C/D layout (16x16x32): col = lane&15, row = (lane>>4)*4 + reg.
  float p2r[4];
  #pragma unroll
  for (int j = 0; j < 4; ++j) p2r[j] = p2[N0 + wc * 64 + j * 16 + lm];
  float x2r[16];
  #pragma unroll
  for (int i = 0; i < 4; ++i)
    #pragma unroll
    for (int v = 0; v < 4; ++v)
      x2r[i * 4 + v] = x2[M0 + wr * 64 + i * 16 + q * 4 + v];

  #pragma unroll
  for (int i = 0; i < 4; ++i) {
    const int mbase = M0 + wr * 64 + i * 16 + q * 4;
    #pragma unroll
    for (int v = 0; v < 4; ++v) {
      float* orow = out + (size_t)(mbase + v) * P_ROWS + N0 + wc * 64 + lm;
      #pragma unroll
      for (int j = 0; j < 4; ++j) {
        float d2 = x2r[i * 4 + v] + p2r[j] - 2.0f * acc[i][j][v];
        d2 = fmaxf(d2, 0.0f);
        const float dist = sqrtf(d2);
        orow[j * 16] = __expf(-0.5f * dist);   // denom = 2*sigma^2 = 2
      }
    }
  }
}

// ---------------------------------------------------------------------------
extern "C" void kernel_launch(void* const* d_in, const int* in_sizes, int n_in,
                              void* d_out, int out_size, void* d_ws, size_t ws_size,
                              hipStream_t stream) {
  const float* x = (const float*)d_in[0];
  const float* p = (const float*)d_in[1];
  float* out = (float*)d_out;

  // ws layout: xbf (4 MiB) | pbf (4 MiB) | x2 (32 KiB) | p2 (32 KiB)
  char* ws = (char*)d_ws;
  unsigned short* xbf = (unsigned short*)ws;
  unsigned short* pbf = (unsigned short*)(ws + (size_t)B_ROWS * FDIM * 2);
  float* x2 = (float*)(ws + (size_t)(B_ROWS + P_ROWS) * FDIM * 2);
  float* p2 = x2 + B_ROWS;

  prep_kernel<<<dim3(B_ROWS + P_ROWS), dim3(64), 0, stream>>>(x, p, xbf, pbf, x2, p2);

  dim3 grid(P_ROWS / BN, B_ROWS / BM);  // 64 x 64 = 4096 blocks
  gauss_kernel<<<grid, dim3(256), 0, stream>>>(xbf, pbf, x2, p2, out);
}